// Round 7
// baseline (1928.593 us; speedup 1.0000x reference)
//
#include <hip/hip_runtime.h>

#define TT 2000
#define NB 100
#define N1 100
#define KIN 784
#define CT1 1998      // L1 steps 1..1998 consume z1 rows 0..1997
#define NC1 10000     // 100 batches x 100 neurons
#define CT2 1999      // L2 steps 1..1999 consume z2 rows 0..1998
#define NC2 1000      // 100 batches x 10 outputs

// ---------- fast math (v_rcp_f32 ~1 ulp; 138x accuracy headroom measured) ----------
__device__ __forceinline__ float rcp_f(float d) { return __builtin_amdgcn_rcpf(d); }
__device__ __forceinline__ float sigmoid3(float V) {
  return rcp_f(1.0f + __expf((20.0f - V) * (1.0f / 3.0f)));
}
__device__ __forceinline__ float gate_u(float a, float b, float p) {
  float s = 0.005f * (a + b);
  return (a * 0.01f + (1.0f - s) * p) * rcp_f(s + 1.0f);
}
// Crank-Nicolson HH step; N/M backward rates share the forward exp
// (bN = 0.1*u*aN, bM = (0.124/0.182)*u*aM); singularity patches preserved.
__device__ __forceinline__ void hh_step(float& V, float& m, float& n, float& h,
                                        float& y, float zk) {
  float p1 = 40.0f * m * m * m * h;
  float nn2 = n * n;
  float p2 = 35.0f * nn2 * nn2;
  float Gs = 0.005f * (p1 + p2 + 0.3f + 0.04f * y);
  float E = p1 * 55.0f + p2 * (-77.0f) + (0.3f * (-65.0f));
  float Vn = (V * (1.0f - Gs) + 0.01f * (E + 1.5f)) * rcp_f(1.0f + Gs);

  float u_n = __expf((25.0f - Vn) * (1.0f / 9.0f));
  float u_m = __expf((-Vn - 35.0f) * (1.0f / 9.0f));
  float aH  = 0.25f * __expf((-Vn - 90.0f) * (1.0f / 12.0f));
  float bH  = 0.25f * __expf((Vn + 34.0f) * (1.0f / 12.0f));
  float dn = 1.0f - u_n, dm = 1.0f - u_m;
  float aN, bN, aM, bM;
  if (dn == 0.0f) { aN = 0.18f; bN = 0.018f; }
  else { aN = 0.02f * (Vn - 25.0f) * rcp_f(dn); bN = 0.1f * u_n * aN; }
  if (dm == 0.0f) { aM = 1.638f; bM = 1.116f; }
  else { aM = 0.182f * (Vn + 35.0f) * rcp_f(dm); bM = 0.6813187f * u_m * aM; }

  m = gate_u(aM, bM, m);
  n = gate_u(aN, bN, n);
  h = gate_u(aH, bH, h);
  y = gate_u(zk, 0.1f, y);
  V = Vn;
}

// ---------- GEMM: z1s[t][b*100+n] = sum_k batch[b][t][k] * W1[n][k] ----------
// 128x100 tile, K-tile 16, 256 threads (proven R1 structure; only the store
// target layout changed to [t][c] for phase-A coalescing).
__global__ __launch_bounds__(256) void gemm_z1(const float* __restrict__ batch,
                                               const float* __restrict__ W1,
                                               float* __restrict__ z1s) {
  __shared__ float As[16][128];
  __shared__ float Bs[100][16];
  const int tid = threadIdx.x;
  const int r = tid & 63;
  const int g = tid >> 6;
  const int c0 = g * 25;
  const int row0 = blockIdx.x * 128;
  const int M = NB * CT1;

  int fr0 = row0 + (tid >> 2);
  int fr1 = fr0 + 64;
  int cr0 = fr0 < M ? fr0 : (M - 1);
  int cr1 = fr1 < M ? fr1 : (M - 1);
  const float* srcA0 = batch + ((size_t)(cr0 / CT1) * TT + (cr0 % CT1)) * KIN + (tid & 3) * 4;
  const float* srcA1 = batch + ((size_t)(cr1 / CT1) * TT + (cr1 % CT1)) * KIN + (tid & 3) * 4;
  const float* srcB0 = W1 + (size_t)(tid >> 2) * KIN + (tid & 3) * 4;
  const bool hasB1 = (tid < 144);
  const float* srcB1 = W1 + (size_t)((tid >> 2) + 64) * KIN + (tid & 3) * 4;

  float acc[50];
#pragma unroll
  for (int i = 0; i < 50; ++i) acc[i] = 0.0f;

  for (int kt = 0; kt < KIN; kt += 16) {
    float4 a0 = *(const float4*)(srcA0 + kt);
    float4 a1 = *(const float4*)(srcA1 + kt);
    float4 b0 = *(const float4*)(srcB0 + kt);
    float4 b1 = make_float4(0.f, 0.f, 0.f, 0.f);
    if (hasB1) b1 = *(const float4*)(srcB1 + kt);
    __syncthreads();
    {
      int kq4 = (tid & 3) * 4;
      int wr = tid >> 2;
      As[kq4 + 0][wr] = a0.x; As[kq4 + 1][wr] = a0.y;
      As[kq4 + 2][wr] = a0.z; As[kq4 + 3][wr] = a0.w;
      As[kq4 + 0][wr + 64] = a1.x; As[kq4 + 1][wr + 64] = a1.y;
      As[kq4 + 2][wr + 64] = a1.z; As[kq4 + 3][wr + 64] = a1.w;
      *(float4*)&Bs[wr][kq4] = b0;
      if (hasB1) *(float4*)&Bs[wr + 64][kq4] = b1;
    }
    __syncthreads();
#pragma unroll
    for (int kk = 0; kk < 16; kk += 4) {
      float a0r[4], a1r[4];
#pragma unroll
      for (int i = 0; i < 4; ++i) { a0r[i] = As[kk + i][r]; a1r[i] = As[kk + i][r + 64]; }
#pragma unroll
      for (int j = 0; j < 25; ++j) {
        float4 bv = *(const float4*)&Bs[c0 + j][kk];
        acc[j]      += a0r[0] * bv.x; acc[j]      += a0r[1] * bv.y;
        acc[j]      += a0r[2] * bv.z; acc[j]      += a0r[3] * bv.w;
        acc[25 + j] += a1r[0] * bv.x; acc[25 + j] += a1r[1] * bv.y;
        acc[25 + j] += a1r[2] * bv.z; acc[25 + j] += a1r[3] * bv.w;
      }
    }
  }
  int rg0 = row0 + r, rg1 = rg0 + 64;
  if (rg0 < M) {
    int b0i = rg0 / CT1, t0i = rg0 - b0i * CT1;
    float* dst = z1s + (size_t)t0i * NC1 + b0i * N1 + c0;
#pragma unroll
    for (int j = 0; j < 25; ++j) dst[j] = acc[j];
  }
  if (rg1 < M) {
    int b1i = rg1 / CT1, t1i = rg1 - b1i * CT1;
    float* dst = z1s + (size_t)t1i * NC1 + b1i * N1 + c0;
#pragma unroll
    for (int j = 0; j < 25; ++j) dst[j] = acc[25 + j];
  }
}

// ---------- phase A: 10,000 independent L1 scans, 1 lane each ----------
// No LDS, no barriers. 40 blocks x 256 thr -> ~1 wave/SIMD. Coalesced
// z reads / T1 writes; z prefetch distance 3 hides HBM/L2 latency.
__global__ __launch_bounds__(256) void hh_l1(const float* __restrict__ z1s,
                                             float* __restrict__ T1s) {
  int c = blockIdx.x * 256 + threadIdx.x;
  if (c >= NC1) return;
  float V = -70.f, m = 0.f, n = 0.f, h = 1.f, y = 0.f;
  T1s[c] = sigmoid3(-70.f);                 // T1 row 0 (from V0)
  const float* zp = z1s + c;
  float* tp = T1s + NC1 + c;                // T1 row 1
  float za = zp[0];
  float zb = zp[(size_t)NC1];
  float zc = zp[(size_t)2 * NC1];
  zp += (size_t)3 * NC1;
  for (int k = 1; k <= CT1; ++k) {
    float zn = 0.f;
    if (k + 2 < CT1) zn = *zp;              // z row k+2 (rows 0..CT1-1 valid)
    hh_step(V, m, n, h, y, za);             // consumes z row k-1
    *tp = sigmoid3(V);
    tp += NC1;
    za = zb; zb = zc; zc = zn;
    zp += NC1;
  }
}

// ---------- phase B: z2s[r][o] = sum_n T1s[r][n] * W2[o][n], r=(t,b) ----------
// r indexes 100-float rows of T1s directly: T1s[(t*100+b)*100 + n];
// output row = r*10. W2 staged in LDS; all-lane-same-address reads broadcast.
__global__ __launch_bounds__(256) void z2_gemm(const float* __restrict__ T1s,
                                               const float* __restrict__ W2,
                                               float* __restrict__ z2s) {
  __shared__ float w2[1000];
  const int tid = threadIdx.x;
  if (tid < 250) *(float4*)&w2[tid * 4] = *(const float4*)&W2[tid * 4];
  __syncthreads();
  const int R = CT2 * NB;                   // 199,900 rows
  int r = blockIdx.x * 256 + tid;
  if (r >= R) return;
  const float* in = T1s + (size_t)r * 100;
  float acc[10];
#pragma unroll
  for (int o = 0; o < 10; ++o) acc[o] = 0.f;
  for (int k4 = 0; k4 < 25; ++k4) {
    float4 v = *(const float4*)(in + k4 * 4);
#pragma unroll
    for (int o = 0; o < 10; ++o) {
      float4 w = *(const float4*)&w2[o * 100 + k4 * 4];
      acc[o] += v.x * w.x + v.y * w.y + v.z * w.z + v.w * w.w;
    }
  }
  float* op = z2s + (size_t)r * 10;
#pragma unroll
  for (int o = 0; o < 10; o += 2) *(float2*)(op + o) = make_float2(acc[o], acc[o + 1]);
}

// ---------- phase C: 1000 independent L2 scans, 1 lane each ----------
__global__ __launch_bounds__(64) void hh_l2(const float* __restrict__ z2s,
                                            float* __restrict__ out) {
  int c2 = blockIdx.x * 64 + threadIdx.x;
  if (c2 >= NC2) return;
  int b = c2 / 10, o = c2 - b * 10;
  float V = -70.f, m = 0.f, n = 0.f, h = 1.f, y = 1.f;   // y0 = 1.0 for layer 2
  float* op = out + (size_t)b * TT * 10 + o;
  *op = sigmoid3(-70.f);                    // out row 0
  op += 10;
  const float* zp = z2s + c2;
  float za = zp[0];
  float zb = zp[(size_t)NC2];
  float zc = zp[(size_t)2 * NC2];
  zp += (size_t)3 * NC2;
  for (int k = 1; k <= CT2; ++k) {
    float zn = 0.f;
    if (k + 2 < CT2) zn = *zp;              // z2 row k+2 (rows 0..CT2-1 valid)
    hh_step(V, m, n, h, y, za);             // consumes z2 row k-1
    *op = sigmoid3(V);
    op += 10;
    za = zb; zb = zc; zc = zn;
    zp += NC2;
  }
}

extern "C" void kernel_launch(void* const* d_in, const int* in_sizes, int n_in,
                              void* d_out, int out_size, void* d_ws, size_t ws_size,
                              hipStream_t stream) {
  (void)in_sizes; (void)n_in; (void)out_size; (void)ws_size;
  const float* batch = (const float*)d_in[0];
  const float* W1 = (const float*)d_in[1];
  const float* W2 = (const float*)d_in[2];
  float* out = (float*)d_out;

  // ws layout (needs ~168 MB; ws is ~2.45 GB): z1s | T1s | z2s
  float* z1s = (float*)d_ws;                                  // CT1 x NC1
  float* T1s = z1s + (size_t)CT1 * NC1;                       // CT2 x NC1 (rows 0..1998)
  float* z2s = T1s + (size_t)CT2 * NC1;                       // CT2 x NC2

  {
    int M = NB * CT1;
    dim3 gg((unsigned)((M + 127) / 128));
    gemm_z1<<<gg, dim3(256), 0, stream>>>(batch, W1, z1s);
  }
  hh_l1<<<dim3((NC1 + 255) / 256), dim3(256), 0, stream>>>(z1s, T1s);
  {
    int R = CT2 * NB;
    z2_gemm<<<dim3((unsigned)((R + 255) / 256)), dim3(256), 0, stream>>>(T1s, W2, z2s);
  }
  hh_l2<<<dim3((NC2 + 63) / 64), dim3(64), 0, stream>>>(z2s, out);
}

// Round 8
// 1435.270 us; speedup vs baseline: 1.3437x; 1.3437x over previous
//
#include <hip/hip_runtime.h>

#define TT 2000
#define NB 100
#define N1 100
#define KIN 784
#define CT1 1998      // L1 steps 1..1998 consume z1 rows 0..1997
#define NC1 10000     // 100 batches x 100 neurons
#define CT2 1999      // L2 steps 1..1999 consume z2 rows 0..1998
#define NC2 1000      // 100 batches x 10 outputs

// ---------- fast math (v_rcp_f32 ~1 ulp; 138x accuracy headroom measured) ----------
__device__ __forceinline__ float rcp_f(float d) { return __builtin_amdgcn_rcpf(d); }
__device__ __forceinline__ float sigmoid3(float V) {
  return rcp_f(1.0f + __expf((20.0f - V) * (1.0f / 3.0f)));
}
__device__ __forceinline__ float gate_u(float a, float b, float p) {
  float s = 0.005f * (a + b);
  return (a * 0.01f + (1.0f - s) * p) * rcp_f(s + 1.0f);
}
// Crank-Nicolson HH step. n/m gates use the rescaled form: multiply gate
// num/den by (1-u) so the rate-rcp and gate-rcp fuse into ONE rcp.
//   aN = Bn/dn, bN = 0.1*u_n*aN  ->  n' = (Bn*DT + (dn-Pn) n)/(dn+Pn),
//   Pn = 0.005*Bn*(1+0.1*u_n)   (algebraically identical)
// Singularity patch dn==0 (<=> u_n==1): substituting Bn=0.18 (=0.02*9, the
// analytic limit), dn=1 reproduces the reference branch EXACTLY; same for
// m with Am=1.638, and bM = (0.124/0.182)*u_m*aM.
__device__ __forceinline__ void hh_step(float& V, float& m, float& n, float& h,
                                        float& y, float zk) {
  float p1 = 40.0f * m * m * m * h;
  float nn2 = n * n;
  float p2 = 35.0f * nn2 * nn2;
  float Gs = 0.005f * (p1 + p2 + 0.3f + 0.04f * y);
  float E = p1 * 55.0f + p2 * (-77.0f) + (0.3f * (-65.0f));
  float Vn = (V * (1.0f - Gs) + 0.01f * (E + 1.5f)) * rcp_f(1.0f + Gs);

  float u_n = __expf((25.0f - Vn) * (1.0f / 9.0f));
  float u_m = __expf((-Vn - 35.0f) * (1.0f / 9.0f));
  float aH  = 0.25f * __expf((-Vn - 90.0f) * (1.0f / 12.0f));
  float bH  = 0.25f * __expf((Vn + 34.0f) * (1.0f / 12.0f));

  float dn = 1.0f - u_n, dm = 1.0f - u_m;
  float Bn = 0.02f * (Vn - 25.0f);
  float Am = 0.182f * (Vn + 35.0f);
  if (dn == 0.0f) { Bn = 0.18f;  dn = 1.0f; }
  if (dm == 0.0f) { Am = 1.638f; dm = 1.0f; }
  float Pn = 0.005f * Bn * (1.0f + 0.1f * u_n);
  float Pm = 0.005f * Am * (1.0f + 0.6813187f * u_m);
  n = (Bn * 0.01f + (dn - Pn) * n) * rcp_f(dn + Pn);
  m = (Am * 0.01f + (dm - Pm) * m) * rcp_f(dm + Pm);
  h = gate_u(aH, bH, h);
  y = gate_u(zk, 0.1f, y);
  V = Vn;
}

// ---------- GEMM: z1s[t][b*100+n] = sum_k batch[b][t][k] * W1[n][k] ----------
// 128x100 tile, K-tile 16, 256 threads (proven R1 structure).
__global__ __launch_bounds__(256) void gemm_z1(const float* __restrict__ batch,
                                               const float* __restrict__ W1,
                                               float* __restrict__ z1s) {
  __shared__ float As[16][128];
  __shared__ float Bs[100][16];
  const int tid = threadIdx.x;
  const int r = tid & 63;
  const int g = tid >> 6;
  const int c0 = g * 25;
  const int row0 = blockIdx.x * 128;
  const int M = NB * CT1;

  int fr0 = row0 + (tid >> 2);
  int fr1 = fr0 + 64;
  int cr0 = fr0 < M ? fr0 : (M - 1);
  int cr1 = fr1 < M ? fr1 : (M - 1);
  const float* srcA0 = batch + ((size_t)(cr0 / CT1) * TT + (cr0 % CT1)) * KIN + (tid & 3) * 4;
  const float* srcA1 = batch + ((size_t)(cr1 / CT1) * TT + (cr1 % CT1)) * KIN + (tid & 3) * 4;
  const float* srcB0 = W1 + (size_t)(tid >> 2) * KIN + (tid & 3) * 4;
  const bool hasB1 = (tid < 144);
  const float* srcB1 = W1 + (size_t)((tid >> 2) + 64) * KIN + (tid & 3) * 4;

  float acc[50];
#pragma unroll
  for (int i = 0; i < 50; ++i) acc[i] = 0.0f;

  for (int kt = 0; kt < KIN; kt += 16) {
    float4 a0 = *(const float4*)(srcA0 + kt);
    float4 a1 = *(const float4*)(srcA1 + kt);
    float4 b0 = *(const float4*)(srcB0 + kt);
    float4 b1 = make_float4(0.f, 0.f, 0.f, 0.f);
    if (hasB1) b1 = *(const float4*)(srcB1 + kt);
    __syncthreads();
    {
      int kq4 = (tid & 3) * 4;
      int wr = tid >> 2;
      As[kq4 + 0][wr] = a0.x; As[kq4 + 1][wr] = a0.y;
      As[kq4 + 2][wr] = a0.z; As[kq4 + 3][wr] = a0.w;
      As[kq4 + 0][wr + 64] = a1.x; As[kq4 + 1][wr + 64] = a1.y;
      As[kq4 + 2][wr + 64] = a1.z; As[kq4 + 3][wr + 64] = a1.w;
      *(float4*)&Bs[wr][kq4] = b0;
      if (hasB1) *(float4*)&Bs[wr + 64][kq4] = b1;
    }
    __syncthreads();
#pragma unroll
    for (int kk = 0; kk < 16; kk += 4) {
      float a0r[4], a1r[4];
#pragma unroll
      for (int i = 0; i < 4; ++i) { a0r[i] = As[kk + i][r]; a1r[i] = As[kk + i][r + 64]; }
#pragma unroll
      for (int j = 0; j < 25; ++j) {
        float4 bv = *(const float4*)&Bs[c0 + j][kk];
        acc[j]      += a0r[0] * bv.x; acc[j]      += a0r[1] * bv.y;
        acc[j]      += a0r[2] * bv.z; acc[j]      += a0r[3] * bv.w;
        acc[25 + j] += a1r[0] * bv.x; acc[25 + j] += a1r[1] * bv.y;
        acc[25 + j] += a1r[2] * bv.z; acc[25 + j] += a1r[3] * bv.w;
      }
    }
  }
  int rg0 = row0 + r, rg1 = rg0 + 64;
  if (rg0 < M) {
    int b0i = rg0 / CT1, t0i = rg0 - b0i * CT1;
    float* dst = z1s + (size_t)t0i * NC1 + b0i * N1 + c0;
#pragma unroll
    for (int j = 0; j < 25; ++j) dst[j] = acc[j];
  }
  if (rg1 < M) {
    int b1i = rg1 / CT1, t1i = rg1 - b1i * CT1;
    float* dst = z1s + (size_t)t1i * NC1 + b1i * N1 + c0;
#pragma unroll
    for (int j = 0; j < 25; ++j) dst[j] = acc[25 + j];
  }
}

// ---------- phase A: 10,000 independent L1 scans, 1 lane each ----------
// Windowed 8-deep z prefetch: 8 loads in flight are consumed 8 steps later
// (cover ~8x chain >> HBM/L3 latency). No LDS, no barriers.
__global__ __launch_bounds__(256) void hh_l1(const float* __restrict__ z1s,
                                             float* __restrict__ T1s) {
  int c = blockIdx.x * 256 + threadIdx.x;
  if (c >= NC1) return;
  float V = -70.f, m = 0.f, n = 0.f, h = 1.f, y = 0.f;
  T1s[c] = sigmoid3(-70.f);
  const float* zp = z1s + c;
  float* tp = T1s + NC1 + c;
  float zc[8], zn[8];
#pragma unroll
  for (int j = 0; j < 8; ++j) zc[j] = zp[(size_t)j * NC1];   // rows 0..7
  const int NW = CT1 / 8;          // 249 full windows; tail 6
  for (int i = 0; i < NW; ++i) {
    int nb = (i + 1) * 8;
#pragma unroll
    for (int j = 0; j < 8; ++j) {
      int ix = (nb + j < CT1) ? (nb + j) : 0;                // clamped; unused if OOB
      zn[j] = zp[(size_t)ix * NC1];
    }
#pragma unroll
    for (int j = 0; j < 8; ++j) {
      hh_step(V, m, n, h, y, zc[j]);
      *tp = sigmoid3(V);
      tp += NC1;
    }
#pragma unroll
    for (int j = 0; j < 8; ++j) zc[j] = zn[j];
  }
#pragma unroll
  for (int j = 0; j < 6; ++j) {                              // tail steps 1993..1998
    hh_step(V, m, n, h, y, zc[j]);
    *tp = sigmoid3(V);
    tp += NC1;
  }
}

// ---------- phase B: z2s[r][o] = sum_n T1s[r][n] * W2[o][n], r=(t,b) ----------
__global__ __launch_bounds__(256) void z2_gemm(const float* __restrict__ T1s,
                                               const float* __restrict__ W2,
                                               float* __restrict__ z2s) {
  __shared__ float w2[1000];
  const int tid = threadIdx.x;
  if (tid < 250) *(float4*)&w2[tid * 4] = *(const float4*)&W2[tid * 4];
  __syncthreads();
  const int R = CT2 * NB;                   // 199,900 rows
  int r = blockIdx.x * 256 + tid;
  if (r >= R) return;
  const float* in = T1s + (size_t)r * 100;
  float acc[10];
#pragma unroll
  for (int o = 0; o < 10; ++o) acc[o] = 0.f;
  for (int k4 = 0; k4 < 25; ++k4) {
    float4 v = *(const float4*)(in + k4 * 4);
#pragma unroll
    for (int o = 0; o < 10; ++o) {
      float4 w = *(const float4*)&w2[o * 100 + k4 * 4];
      acc[o] += v.x * w.x + v.y * w.y + v.z * w.z + v.w * w.w;
    }
  }
  float* op = z2s + (size_t)r * 10;
#pragma unroll
  for (int o = 0; o < 10; o += 2) *(float2*)(op + o) = make_float2(acc[o], acc[o + 1]);
}

// ---------- phase C: 1000 independent L2 scans, windowed prefetch ----------
__global__ __launch_bounds__(256) void hh_l2(const float* __restrict__ z2s,
                                             float* __restrict__ out) {
  int c2 = blockIdx.x * 256 + threadIdx.x;
  if (c2 >= NC2) return;
  int b = c2 / 10, o = c2 - b * 10;
  float V = -70.f, m = 0.f, n = 0.f, h = 1.f, y = 1.f;   // y0 = 1.0 for layer 2
  float* op = out + (size_t)b * TT * 10 + o;
  *op = sigmoid3(-70.f);
  op += 10;
  const float* zp = z2s + c2;
  float zc[8], zn[8];
#pragma unroll
  for (int j = 0; j < 8; ++j) zc[j] = zp[(size_t)j * NC2];   // rows 0..7
  const int NW = CT2 / 8;          // 249 full windows; tail 7
  for (int i = 0; i < NW; ++i) {
    int nb = (i + 1) * 8;
#pragma unroll
    for (int j = 0; j < 8; ++j) {
      int ix = (nb + j < CT2) ? (nb + j) : 0;
      zn[j] = zp[(size_t)ix * NC2];
    }
#pragma unroll
    for (int j = 0; j < 8; ++j) {
      hh_step(V, m, n, h, y, zc[j]);
      *op = sigmoid3(V);
      op += 10;
    }
#pragma unroll
    for (int j = 0; j < 8; ++j) zc[j] = zn[j];
  }
#pragma unroll
  for (int j = 0; j < 7; ++j) {                              // tail steps 1993..1999
    hh_step(V, m, n, h, y, zc[j]);
    *op = sigmoid3(V);
    op += 10;
  }
}

extern "C" void kernel_launch(void* const* d_in, const int* in_sizes, int n_in,
                              void* d_out, int out_size, void* d_ws, size_t ws_size,
                              hipStream_t stream) {
  (void)in_sizes; (void)n_in; (void)out_size; (void)ws_size;
  const float* batch = (const float*)d_in[0];
  const float* W1 = (const float*)d_in[1];
  const float* W2 = (const float*)d_in[2];
  float* out = (float*)d_out;

  // ws layout (~168 MB of ~2.45 GB): z1s | T1s | z2s
  float* z1s = (float*)d_ws;                                  // CT1 x NC1
  float* T1s = z1s + (size_t)CT1 * NC1;                       // CT2 x NC1
  float* z2s = T1s + (size_t)CT2 * NC1;                       // CT2 x NC2

  {
    int M = NB * CT1;
    dim3 gg((unsigned)((M + 127) / 128));
    gemm_z1<<<gg, dim3(256), 0, stream>>>(batch, W1, z1s);
  }
  hh_l1<<<dim3((NC1 + 255) / 256), dim3(256), 0, stream>>>(z1s, T1s);
  {
    int R = CT2 * NB;
    z2_gemm<<<dim3((unsigned)((R + 255) / 256)), dim3(256), 0, stream>>>(T1s, W2, z2s);
  }
  hh_l2<<<dim3((NC2 + 255) / 256), dim3(256), 0, stream>>>(z2s, out);
}

// Round 9
// 1066.303 us; speedup vs baseline: 1.8087x; 1.3460x over previous
//
#include <hip/hip_runtime.h>

#define TT 2000
#define NB 100
#define N1 100
#define KIN 784
#define CT1 1998      // L1 steps 1..1998 consume z1 rows 0..1997
#define NC1 10000     // 100 batches x 100 neurons
#define CT2 1999      // L2 steps 1..1999 consume z2 rows 0..1998
#define NC2 1000      // 100 batches x 10 outputs
#define MROWS (NB * CT1)   // 199800 gemm output rows (b*CT1 + t)
#define NPAD 112
#define KPAD 800

typedef __attribute__((ext_vector_type(8))) short bf16x8;
typedef __attribute__((ext_vector_type(4))) float f32x4;

// ---------- fast math ----------
__device__ __forceinline__ float rcp_f(float d) { return __builtin_amdgcn_rcpf(d); }
__device__ __forceinline__ float sigmoid3(float V) {
  return rcp_f(1.0f + __expf((20.0f - V) * (1.0f / 3.0f)));
}
__device__ __forceinline__ float gate_u(float a, float b, float p) {
  float s = 0.005f * (a + b);
  return (a * 0.01f + (1.0f - s) * p) * rcp_f(s + 1.0f);
}
// Crank-Nicolson HH step; n/m gates rescaled by (1-u) to fuse the rate-rcp
// and gate-rcp into one rcp (singularity patches reproduced exactly).
__device__ __forceinline__ void hh_step(float& V, float& m, float& n, float& h,
                                        float& y, float zk) {
  float p1 = 40.0f * m * m * m * h;
  float nn2 = n * n;
  float p2 = 35.0f * nn2 * nn2;
  float Gs = 0.005f * (p1 + p2 + 0.3f + 0.04f * y);
  float E = p1 * 55.0f + p2 * (-77.0f) + (0.3f * (-65.0f));
  float Vn = (V * (1.0f - Gs) + 0.01f * (E + 1.5f)) * rcp_f(1.0f + Gs);

  float u_n = __expf((25.0f - Vn) * (1.0f / 9.0f));
  float u_m = __expf((-Vn - 35.0f) * (1.0f / 9.0f));
  float aH  = 0.25f * __expf((-Vn - 90.0f) * (1.0f / 12.0f));
  float bH  = 0.25f * __expf((Vn + 34.0f) * (1.0f / 12.0f));

  float dn = 1.0f - u_n, dm = 1.0f - u_m;
  float Bn = 0.02f * (Vn - 25.0f);
  float Am = 0.182f * (Vn + 35.0f);
  if (dn == 0.0f) { Bn = 0.18f;  dn = 1.0f; }
  if (dm == 0.0f) { Am = 1.638f; dm = 1.0f; }
  float Pn = 0.005f * Bn * (1.0f + 0.1f * u_n);
  float Pm = 0.005f * Am * (1.0f + 0.6813187f * u_m);
  n = (Bn * 0.01f + (dn - Pn) * n) * rcp_f(dn + Pn);
  m = (Am * 0.01f + (dm - Pm) * m) * rcp_f(dm + Pm);
  h = gate_u(aH, bH, h);
  y = gate_u(zk, 0.1f, y);
  V = Vn;
}

// ---------- bf16 split helpers (exact 2-term split) ----------
__device__ __forceinline__ short bf16rne(float x) {
  unsigned u = __builtin_bit_cast(unsigned, x);
  unsigned r = u + 0x7fffu + ((u >> 16) & 1u);
  return (short)(r >> 16);
}
__device__ __forceinline__ float bf2f(short s) {
  unsigned u = ((unsigned)(unsigned short)s) << 16;
  return __builtin_bit_cast(float, u);
}
__device__ __forceinline__ void bsplit(float x, short& h, short& l) {
  h = bf16rne(x);
  l = bf16rne(x - bf2f(h));
}

// ---------- prep: W1 -> padded bf16 hi/lo [NPAD][KPAD] ----------
__global__ __launch_bounds__(256) void prep_w1(const float* __restrict__ W1,
                                               short* __restrict__ W1h,
                                               short* __restrict__ W1l) {
  int idx = blockIdx.x * 256 + threadIdx.x;
  if (idx >= NPAD * KPAD) return;
  int nrow = idx / KPAD, k = idx - nrow * KPAD;
  float v = (nrow < N1 && k < KIN) ? W1[nrow * KIN + k] : 0.0f;
  short h, l; bsplit(v, h, l);
  W1h[idx] = h; W1l[idx] = l;
}

// ---------- MFMA GEMM: z1s[b*CT1+t][n] = sum_k batch[b][t][k] * W1[n][k] ----------
// Split-bf16 3-pass (Ah*Bh + Ah*Bl + Al*Bh) with fp32 accumulation.
// Block: 256 thr = 4 waves; tile 128(M) x 112(N); K-tile 32 (KPAD=800 -> 25 tiles).
// Wave w: M rows [w*32, w*32+32) as 2 16-row subtiles x 7 N-subtiles.
__global__ __launch_bounds__(256) void gemm_z1(const float* __restrict__ batch,
                                               const short* __restrict__ W1h,
                                               const short* __restrict__ W1l,
                                               float* __restrict__ z1s) {
  __shared__ short AsH[128][32];
  __shared__ short AsL[128][32];
  __shared__ short BsH[NPAD][32];
  __shared__ short BsL[NPAD][32];

  const int tid = threadIdx.x;
  const int row0 = blockIdx.x * 128;

  // A staging address (fixed per thread): row = tid>>1, k-half = (tid&1)*16
  const int srow = tid >> 1;
  const int kc = (tid & 1) * 16;
  int gr = row0 + srow;
  int cr = gr < MROWS ? gr : (MROWS - 1);
  int bb = cr / CT1, tt = cr - bb * CT1;
  const float* aSrc = batch + ((size_t)bb * TT + tt) * KIN + kc;

  // B staging: threads 0..223: row = tid>>1, k-half = (tid&1)*16
  const int brow = tid >> 1;
  const bool bAct = (tid < 224);

  f32x4 acc[2][7];
#pragma unroll
  for (int mt = 0; mt < 2; ++mt)
#pragma unroll
    for (int nt = 0; nt < 7; ++nt) acc[mt][nt] = (f32x4){0.f, 0.f, 0.f, 0.f};

  const int w = tid >> 6;
  const int lane = tid & 63;
  const int lr = lane & 15;
  const int kg = lane >> 4;

  for (int kt = 0; kt < KPAD; kt += 32) {
    // ---- load A (fp32) and B (bf16 hi/lo) to registers ----
    int k0 = kt + kc;
    float4 a0 = make_float4(0.f, 0.f, 0.f, 0.f), a1 = a0, a2 = a0, a3 = a0;
    if (k0 < KIN) {
      a0 = *(const float4*)(aSrc + kt);
      a1 = *(const float4*)(aSrc + kt + 4);
      a2 = *(const float4*)(aSrc + kt + 8);
      a3 = *(const float4*)(aSrc + kt + 12);
    }
    int4 bh0, bh1, bl0, bl1;
    if (bAct) {
      const short* sh = W1h + (size_t)brow * KPAD + kt + kc;
      const short* sl = W1l + (size_t)brow * KPAD + kt + kc;
      bh0 = *(const int4*)(sh);
      bh1 = *(const int4*)(sh + 8);
      bl0 = *(const int4*)(sl);
      bl1 = *(const int4*)(sl + 8);
    }
    __syncthreads();   // previous tile's compute done
    {
      float av[16] = {a0.x, a0.y, a0.z, a0.w, a1.x, a1.y, a1.z, a1.w,
                      a2.x, a2.y, a2.z, a2.w, a3.x, a3.y, a3.z, a3.w};
      bf16x8 h0, h1, l0, l1;
#pragma unroll
      for (int i = 0; i < 8; ++i) {
        short hh, ll;
        bsplit(av[i], hh, ll);     h0[i] = hh; l0[i] = ll;
        bsplit(av[8 + i], hh, ll); h1[i] = hh; l1[i] = ll;
      }
      *(bf16x8*)&AsH[srow][kc] = h0;
      *(bf16x8*)&AsH[srow][kc + 8] = h1;
      *(bf16x8*)&AsL[srow][kc] = l0;
      *(bf16x8*)&AsL[srow][kc + 8] = l1;
      if (bAct) {
        *(int4*)&BsH[brow][kc] = bh0;
        *(int4*)&BsH[brow][kc + 8] = bh1;
        *(int4*)&BsL[brow][kc] = bl0;
        *(int4*)&BsL[brow][kc + 8] = bl1;
      }
    }
    __syncthreads();
    // ---- MFMA compute ----
    bf16x8 aH0 = *(bf16x8*)&AsH[w * 32 + lr][kg * 8];
    bf16x8 aH1 = *(bf16x8*)&AsH[w * 32 + 16 + lr][kg * 8];
    bf16x8 aL0 = *(bf16x8*)&AsL[w * 32 + lr][kg * 8];
    bf16x8 aL1 = *(bf16x8*)&AsL[w * 32 + 16 + lr][kg * 8];
#pragma unroll
    for (int nt = 0; nt < 7; ++nt) {
      bf16x8 bH = *(bf16x8*)&BsH[nt * 16 + lr][kg * 8];
      bf16x8 bL = *(bf16x8*)&BsL[nt * 16 + lr][kg * 8];
      acc[0][nt] = __builtin_amdgcn_mfma_f32_16x16x32_bf16(aH0, bH, acc[0][nt], 0, 0, 0);
      acc[0][nt] = __builtin_amdgcn_mfma_f32_16x16x32_bf16(aH0, bL, acc[0][nt], 0, 0, 0);
      acc[0][nt] = __builtin_amdgcn_mfma_f32_16x16x32_bf16(aL0, bH, acc[0][nt], 0, 0, 0);
      acc[1][nt] = __builtin_amdgcn_mfma_f32_16x16x32_bf16(aH1, bH, acc[1][nt], 0, 0, 0);
      acc[1][nt] = __builtin_amdgcn_mfma_f32_16x16x32_bf16(aH1, bL, acc[1][nt], 0, 0, 0);
      acc[1][nt] = __builtin_amdgcn_mfma_f32_16x16x32_bf16(aL1, bH, acc[1][nt], 0, 0, 0);
    }
  }

  // ---- store: D col = lane&15, row = 4*(lane>>4)+reg ----
#pragma unroll
  for (int nt = 0; nt < 7; ++nt) {
    int n = nt * 16 + lr;
    if (n < 100) {
#pragma unroll
      for (int mt = 0; mt < 2; ++mt) {
        int rbase = row0 + w * 32 + mt * 16 + kg * 4;
        f32x4 d = acc[mt][nt];
#pragma unroll
        for (int rr = 0; rr < 4; ++rr) {
          int rg = rbase + rr;
          if (rg < MROWS) z1s[(size_t)rg * 100 + n] = d[rr];
        }
      }
    }
  }
}

// ---------- phase A: 10,000 independent L1 scans, 1 lane each ----------
// z1s row-major [b*CT1+t][100]; lane (b,n) reads stride-400B; 8-deep prefetch.
__global__ __launch_bounds__(256) void hh_l1(const float* __restrict__ z1s,
                                             float* __restrict__ T1s) {
  int c = blockIdx.x * 256 + threadIdx.x;
  if (c >= NC1) return;
  int b = c / 100, n = c - b * 100;
  float V = -70.f, m = 0.f, nn = 0.f, h = 1.f, y = 0.f;
  T1s[c] = sigmoid3(-70.f);
  const float* zp = z1s + (size_t)b * CT1 * 100 + n;
  float* tp = T1s + NC1 + c;
  float zc[8], zn[8];
#pragma unroll
  for (int j = 0; j < 8; ++j) zc[j] = zp[(size_t)j * 100];
  const int NW = CT1 / 8;          // 249 full windows; tail 6
  for (int i = 0; i < NW; ++i) {
    int nb = (i + 1) * 8;
#pragma unroll
    for (int j = 0; j < 8; ++j) {
      int ix = (nb + j < CT1) ? (nb + j) : 0;
      zn[j] = zp[(size_t)ix * 100];
    }
#pragma unroll
    for (int j = 0; j < 8; ++j) {
      hh_step(V, m, nn, h, y, zc[j]);
      *tp = sigmoid3(V);
      tp += NC1;
    }
#pragma unroll
    for (int j = 0; j < 8; ++j) zc[j] = zn[j];
  }
#pragma unroll
  for (int j = 0; j < 6; ++j) {
    hh_step(V, m, nn, h, y, zc[j]);
    *tp = sigmoid3(V);
    tp += NC1;
  }
}

// ---------- phase B: z2s[r][o] = sum_n T1s[r][n] * W2[o][n], r=(t,b) ----------
__global__ __launch_bounds__(256) void z2_gemm(const float* __restrict__ T1s,
                                               const float* __restrict__ W2,
                                               float* __restrict__ z2s) {
  __shared__ float w2[1000];
  const int tid = threadIdx.x;
  if (tid < 250) *(float4*)&w2[tid * 4] = *(const float4*)&W2[tid * 4];
  __syncthreads();
  const int R = CT2 * NB;
  int r = blockIdx.x * 256 + tid;
  if (r >= R) return;
  const float* in = T1s + (size_t)r * 100;
  float acc[10];
#pragma unroll
  for (int o = 0; o < 10; ++o) acc[o] = 0.f;
  for (int k4 = 0; k4 < 25; ++k4) {
    float4 v = *(const float4*)(in + k4 * 4);
#pragma unroll
    for (int o = 0; o < 10; ++o) {
      float4 w = *(const float4*)&w2[o * 100 + k4 * 4];
      acc[o] += v.x * w.x + v.y * w.y + v.z * w.z + v.w * w.w;
    }
  }
  float* op = z2s + (size_t)r * 10;
#pragma unroll
  for (int o = 0; o < 10; o += 2) *(float2*)(op + o) = make_float2(acc[o], acc[o + 1]);
}

// ---------- phase C: 1000 independent L2 scans, windowed prefetch ----------
__global__ __launch_bounds__(256) void hh_l2(const float* __restrict__ z2s,
                                             float* __restrict__ out) {
  int c2 = blockIdx.x * 256 + threadIdx.x;
  if (c2 >= NC2) return;
  int b = c2 / 10, o = c2 - b * 10;
  float V = -70.f, m = 0.f, n = 0.f, h = 1.f, y = 1.f;
  float* op = out + (size_t)b * TT * 10 + o;
  *op = sigmoid3(-70.f);
  op += 10;
  const float* zp = z2s + c2;
  float zc[8], zn[8];
#pragma unroll
  for (int j = 0; j < 8; ++j) zc[j] = zp[(size_t)j * NC2];
  const int NW = CT2 / 8;          // 249 full windows; tail 7
  for (int i = 0; i < NW; ++i) {
    int nb = (i + 1) * 8;
#pragma unroll
    for (int j = 0; j < 8; ++j) {
      int ix = (nb + j < CT2) ? (nb + j) : 0;
      zn[j] = zp[(size_t)ix * NC2];
    }
#pragma unroll
    for (int j = 0; j < 8; ++j) {
      hh_step(V, m, n, h, y, zc[j]);
      *op = sigmoid3(V);
      op += 10;
    }
#pragma unroll
    for (int j = 0; j < 8; ++j) zc[j] = zn[j];
  }
#pragma unroll
  for (int j = 0; j < 7; ++j) {
    hh_step(V, m, n, h, y, zc[j]);
    *op = sigmoid3(V);
    op += 10;
  }
}

extern "C" void kernel_launch(void* const* d_in, const int* in_sizes, int n_in,
                              void* d_out, int out_size, void* d_ws, size_t ws_size,
                              hipStream_t stream) {
  (void)in_sizes; (void)n_in; (void)out_size; (void)ws_size;
  const float* batch = (const float*)d_in[0];
  const float* W1 = (const float*)d_in[1];
  const float* W2 = (const float*)d_in[2];
  float* out = (float*)d_out;

  // ws layout (~168 MB of ~2.45 GB): z1s | T1s | z2s | W1h | W1l
  float* z1s = (float*)d_ws;                                  // MROWS x 100
  float* T1s = z1s + (size_t)MROWS * 100;                     // CT2 x NC1
  float* z2s = T1s + (size_t)CT2 * NC1;                       // CT2 x NC2
  short* W1h = (short*)(z2s + (size_t)CT2 * NC2);             // NPAD x KPAD bf16
  short* W1l = W1h + (size_t)NPAD * KPAD;

  prep_w1<<<dim3((NPAD * KPAD + 255) / 256), dim3(256), 0, stream>>>(W1, W1h, W1l);
  {
    int nblk = (MROWS + 127) / 128;
    gemm_z1<<<dim3((unsigned)nblk), dim3(256), 0, stream>>>(batch, W1h, W1l, z1s);
  }
  hh_l1<<<dim3((NC1 + 255) / 256), dim3(256), 0, stream>>>(z1s, T1s);
  {
    int R = CT2 * NB;
    z2_gemm<<<dim3((unsigned)((R + 255) / 256)), dim3(256), 0, stream>>>(T1s, W2, z2s);
  }
  hh_l2<<<dim3((NC2 + 255) / 256), dim3(256), 0, stream>>>(z2s, out);
}

// Round 10
// 954.729 us; speedup vs baseline: 2.0200x; 1.1169x over previous
//
#include <hip/hip_runtime.h>

#define TT 2000
#define NB 100
#define N1 100
#define KIN 784
#define CT1 1998      // L1 steps 1..1998 consume z1 rows 0..1997
#define NC1 10000     // 100 batches x 100 neurons
#define CT2 1999      // L2 steps 1..1999 consume z2 rows 0..1998
#define NC2 1000      // 100 batches x 10 outputs
#define NPAD 112
#define KPAD 800
#define S1 128        // chunk size (steps / t-rows per pipeline stage)
#define NCHUNK 16     // ceil(1998/128)

typedef __attribute__((ext_vector_type(8))) short bf16x8;
typedef __attribute__((ext_vector_type(4))) float f32x4;

// ---------- fast math (identical to R8) ----------
__device__ __forceinline__ float rcp_f(float d) { return __builtin_amdgcn_rcpf(d); }
__device__ __forceinline__ float sigmoid3(float V) {
  return rcp_f(1.0f + __expf((20.0f - V) * (1.0f / 3.0f)));
}
__device__ __forceinline__ float gate_u(float a, float b, float p) {
  float s = 0.005f * (a + b);
  return (a * 0.01f + (1.0f - s) * p) * rcp_f(s + 1.0f);
}
__device__ __forceinline__ void hh_step(float& V, float& m, float& n, float& h,
                                        float& y, float zk) {
  float p1 = 40.0f * m * m * m * h;
  float nn2 = n * n;
  float p2 = 35.0f * nn2 * nn2;
  float Gs = 0.005f * (p1 + p2 + 0.3f + 0.04f * y);
  float E = p1 * 55.0f + p2 * (-77.0f) + (0.3f * (-65.0f));
  float Vn = (V * (1.0f - Gs) + 0.01f * (E + 1.5f)) * rcp_f(1.0f + Gs);

  float u_n = __expf((25.0f - Vn) * (1.0f / 9.0f));
  float u_m = __expf((-Vn - 35.0f) * (1.0f / 9.0f));
  float aH  = 0.25f * __expf((-Vn - 90.0f) * (1.0f / 12.0f));
  float bH  = 0.25f * __expf((Vn + 34.0f) * (1.0f / 12.0f));

  float dn = 1.0f - u_n, dm = 1.0f - u_m;
  float Bn = 0.02f * (Vn - 25.0f);
  float Am = 0.182f * (Vn + 35.0f);
  if (dn == 0.0f) { Bn = 0.18f;  dn = 1.0f; }
  if (dm == 0.0f) { Am = 1.638f; dm = 1.0f; }
  float Pn = 0.005f * Bn * (1.0f + 0.1f * u_n);
  float Pm = 0.005f * Am * (1.0f + 0.6813187f * u_m);
  n = (Bn * 0.01f + (dn - Pn) * n) * rcp_f(dn + Pn);
  m = (Am * 0.01f + (dm - Pm) * m) * rcp_f(dm + Pm);
  h = gate_u(aH, bH, h);
  y = gate_u(zk, 0.1f, y);
  V = Vn;
}

// ---------- bf16 split helpers ----------
__device__ __forceinline__ short bf16rne(float x) {
  unsigned u = __builtin_bit_cast(unsigned, x);
  unsigned r = u + 0x7fffu + ((u >> 16) & 1u);
  return (short)(r >> 16);
}
__device__ __forceinline__ float bf2f(short s) {
  unsigned u = ((unsigned)(unsigned short)s) << 16;
  return __builtin_bit_cast(float, u);
}
__device__ __forceinline__ void bsplit(float x, short& h, short& l) {
  h = bf16rne(x);
  l = bf16rne(x - bf2f(h));
}

// ---------- prep: W1 -> padded bf16 hi/lo [NPAD][KPAD] ----------
__global__ __launch_bounds__(256) void prep_w1(const float* __restrict__ W1,
                                               short* __restrict__ W1h,
                                               short* __restrict__ W1l) {
  int idx = blockIdx.x * 256 + threadIdx.x;
  if (idx >= NPAD * KPAD) return;
  int nrow = idx / KPAD, k = idx - nrow * KPAD;
  float v = (nrow < N1 && k < KIN) ? W1[nrow * KIN + k] : 0.0f;
  short h, l; bsplit(v, h, l);
  W1h[idx] = h; W1l[idx] = l;
}

// ---------- gemm chunk body: batch b, t in [k*S1, min((k+1)*S1, CT1)) ----------
// Split-bf16 3-pass MFMA (R8-proven), 128(M)x112(N) tile, K-tile 32.
__device__ void gemm_body(const float* __restrict__ batch, const short* __restrict__ W1h,
                          const short* __restrict__ W1l, float* __restrict__ z1s,
                          int k, int b, char* smem) {
  short (*AsH)[32] = (short(*)[32])(smem);
  short (*AsL)[32] = (short(*)[32])(smem + 8192);
  short (*BsH)[32] = (short(*)[32])(smem + 16384);
  short (*BsL)[32] = (short(*)[32])(smem + 16384 + 7168);

  const int tid = threadIdx.x;
  const int tBeg = k * S1;
  const int tEnd = (tBeg + S1 < CT1) ? (tBeg + S1) : CT1;
  const int rows = tEnd - tBeg;
  const size_t rBeg = (size_t)b * CT1 + tBeg;

  const int srow = tid >> 1;
  const int kc = (tid & 1) * 16;
  int tCl = tBeg + ((srow < rows) ? srow : (rows - 1));
  const float* aSrc = batch + ((size_t)b * TT + tCl) * KIN + kc;
  const int brow = tid >> 1;
  const bool bAct = (tid < 224);

  f32x4 acc[2][7];
#pragma unroll
  for (int mt = 0; mt < 2; ++mt)
#pragma unroll
    for (int nt = 0; nt < 7; ++nt) acc[mt][nt] = (f32x4){0.f, 0.f, 0.f, 0.f};

  const int w = tid >> 6;
  const int lane = tid & 63;
  const int lr = lane & 15;
  const int kg = lane >> 4;

  for (int kt = 0; kt < KPAD; kt += 32) {
    int k0 = kt + kc;
    float4 a0 = make_float4(0.f, 0.f, 0.f, 0.f), a1 = a0, a2 = a0, a3 = a0;
    if (k0 < KIN) {
      a0 = *(const float4*)(aSrc + kt);
      a1 = *(const float4*)(aSrc + kt + 4);
      a2 = *(const float4*)(aSrc + kt + 8);
      a3 = *(const float4*)(aSrc + kt + 12);
    }
    int4 bh0, bh1, bl0, bl1;
    if (bAct) {
      const short* sh = W1h + (size_t)brow * KPAD + kt + kc;
      const short* sl = W1l + (size_t)brow * KPAD + kt + kc;
      bh0 = *(const int4*)(sh);
      bh1 = *(const int4*)(sh + 8);
      bl0 = *(const int4*)(sl);
      bl1 = *(const int4*)(sl + 8);
    }
    __syncthreads();
    {
      float av[16] = {a0.x, a0.y, a0.z, a0.w, a1.x, a1.y, a1.z, a1.w,
                      a2.x, a2.y, a2.z, a2.w, a3.x, a3.y, a3.z, a3.w};
      bf16x8 h0, h1, l0, l1;
#pragma unroll
      for (int i = 0; i < 8; ++i) {
        short hh, ll;
        bsplit(av[i], hh, ll);     h0[i] = hh; l0[i] = ll;
        bsplit(av[8 + i], hh, ll); h1[i] = hh; l1[i] = ll;
      }
      *(bf16x8*)&AsH[srow][kc] = h0;
      *(bf16x8*)&AsH[srow][kc + 8] = h1;
      *(bf16x8*)&AsL[srow][kc] = l0;
      *(bf16x8*)&AsL[srow][kc + 8] = l1;
      if (bAct) {
        *(int4*)&BsH[brow][kc] = bh0;
        *(int4*)&BsH[brow][kc + 8] = bh1;
        *(int4*)&BsL[brow][kc] = bl0;
        *(int4*)&BsL[brow][kc + 8] = bl1;
      }
    }
    __syncthreads();
    bf16x8 aH0 = *(bf16x8*)&AsH[w * 32 + lr][kg * 8];
    bf16x8 aH1 = *(bf16x8*)&AsH[w * 32 + 16 + lr][kg * 8];
    bf16x8 aL0 = *(bf16x8*)&AsL[w * 32 + lr][kg * 8];
    bf16x8 aL1 = *(bf16x8*)&AsL[w * 32 + 16 + lr][kg * 8];
#pragma unroll
    for (int nt = 0; nt < 7; ++nt) {
      bf16x8 bH = *(bf16x8*)&BsH[nt * 16 + lr][kg * 8];
      bf16x8 bL = *(bf16x8*)&BsL[nt * 16 + lr][kg * 8];
      acc[0][nt] = __builtin_amdgcn_mfma_f32_16x16x32_bf16(aH0, bH, acc[0][nt], 0, 0, 0);
      acc[0][nt] = __builtin_amdgcn_mfma_f32_16x16x32_bf16(aH0, bL, acc[0][nt], 0, 0, 0);
      acc[0][nt] = __builtin_amdgcn_mfma_f32_16x16x32_bf16(aL0, bH, acc[0][nt], 0, 0, 0);
      acc[1][nt] = __builtin_amdgcn_mfma_f32_16x16x32_bf16(aH1, bH, acc[1][nt], 0, 0, 0);
      acc[1][nt] = __builtin_amdgcn_mfma_f32_16x16x32_bf16(aH1, bL, acc[1][nt], 0, 0, 0);
      acc[1][nt] = __builtin_amdgcn_mfma_f32_16x16x32_bf16(aL1, bH, acc[1][nt], 0, 0, 0);
    }
  }

#pragma unroll
  for (int nt = 0; nt < 7; ++nt) {
    int n = nt * 16 + lr;
    if (n < 100) {
#pragma unroll
      for (int mt = 0; mt < 2; ++mt) {
        int rloc = w * 32 + mt * 16 + kg * 4;
        f32x4 d = acc[mt][nt];
#pragma unroll
        for (int rr = 0; rr < 4; ++rr) {
          if (rloc + rr < rows) z1s[(rBeg + rloc + rr) * 100 + n] = d[rr];
        }
      }
    }
  }
}

// ---------- L1 scan chunk: steps tBeg+1 .. tEnd (consume z rows tBeg..tEnd-1) ----------
__device__ void l1_body(const float* __restrict__ z1s, float* __restrict__ T1s,
                        float* __restrict__ st, int k, int lb) {
  int c = lb * 256 + threadIdx.x;
  if (c >= NC1) return;
  int b = c / 100, ni = c - b * 100;
  int tBeg = k * S1;
  int tEnd = (tBeg + S1 < CT1) ? (tBeg + S1) : CT1;
  int nsteps = tEnd - tBeg;
  float* SV = st; float* SM = st + NC1; float* SN = st + 2 * NC1;
  float* SH = st + 3 * NC1; float* SY = st + 4 * NC1;
  float V, m, n, h, y;
  if (k == 0) { V = -70.f; m = 0.f; n = 0.f; h = 1.f; y = 0.f; T1s[c] = sigmoid3(-70.f); }
  else { V = SV[c]; m = SM[c]; n = SN[c]; h = SH[c]; y = SY[c]; }
  const float* zp = z1s + ((size_t)b * CT1 + tBeg) * 100 + ni;
  float* tp = T1s + (size_t)(tBeg + 1) * NC1 + c;
  float zc[8], zx[8];
#pragma unroll
  for (int j = 0; j < 8; ++j) { int ix = (j < nsteps) ? j : 0; zc[j] = zp[(size_t)ix * 100]; }
  int NW = nsteps >> 3, tail = nsteps & 7;
  for (int i = 0; i < NW; ++i) {
    int nb0 = (i + 1) * 8;
#pragma unroll
    for (int j = 0; j < 8; ++j) { int ix = (nb0 + j < nsteps) ? (nb0 + j) : 0; zx[j] = zp[(size_t)ix * 100]; }
#pragma unroll
    for (int j = 0; j < 8; ++j) { hh_step(V, m, n, h, y, zc[j]); *tp = sigmoid3(V); tp += NC1; }
#pragma unroll
    for (int j = 0; j < 8; ++j) zc[j] = zx[j];
  }
  for (int j = 0; j < tail; ++j) { hh_step(V, m, n, h, y, zc[j]); *tp = sigmoid3(V); tp += NC1; }
  SV[c] = V; SM[c] = m; SN[c] = n; SH[c] = h; SY[c] = y;
}

// ---------- z2 chunk: rows r = t*NB+b for t in [tBeg, tEnd2) ----------
__device__ void z2_body(const float* __restrict__ T1s, const float* __restrict__ W2,
                        float* __restrict__ z2s, int k, int zb, char* smem) {
  float* w2 = (float*)smem;
  const int tid = threadIdx.x;
  if (tid < 250) *(float4*)&w2[tid * 4] = *(const float4*)&W2[tid * 4];
  __syncthreads();
  int tBeg = k * S1;
  int tEnd = (tBeg + S1 < CT2) ? (tBeg + S1) : CT2;
  int r = tBeg * NB + zb * 256 + tid;
  if (r >= tEnd * NB) return;
  const float* in = T1s + (size_t)r * 100;   // r = t*100 + b indexes T1s[t][b*100..]
  float acc[10];
#pragma unroll
  for (int o = 0; o < 10; ++o) acc[o] = 0.f;
  for (int k4 = 0; k4 < 25; ++k4) {
    float4 v = *(const float4*)(in + k4 * 4);
#pragma unroll
    for (int o = 0; o < 10; ++o) {
      float4 w = *(const float4*)&w2[o * 100 + k4 * 4];
      acc[o] += v.x * w.x + v.y * w.y + v.z * w.z + v.w * w.w;
    }
  }
  float* op = z2s + (size_t)r * 10;
#pragma unroll
  for (int o = 0; o < 10; o += 2) *(float2*)(op + o) = make_float2(acc[o], acc[o + 1]);
}

// ---------- L2 scan chunk ----------
__device__ void l2_body(const float* __restrict__ z2s, float* __restrict__ out,
                        float* __restrict__ st, int k, int lb) {
  int c2 = lb * 256 + threadIdx.x;
  if (c2 >= NC2) return;
  int b = c2 / 10, o = c2 - b * 10;
  int tBeg = k * S1;
  int tEnd = (tBeg + S1 < CT2) ? (tBeg + S1) : CT2;
  int nsteps = tEnd - tBeg;
  float* SV = st; float* SM = st + NC2; float* SN = st + 2 * NC2;
  float* SH = st + 3 * NC2; float* SY = st + 4 * NC2;
  float V, m, n, h, y;
  if (k == 0) {
    V = -70.f; m = 0.f; n = 0.f; h = 1.f; y = 1.f;
    out[(size_t)b * TT * 10 + o] = sigmoid3(-70.f);
  } else { V = SV[c2]; m = SM[c2]; n = SN[c2]; h = SH[c2]; y = SY[c2]; }
  const float* zp = z2s + (size_t)tBeg * NC2 + c2;
  float* op = out + ((size_t)b * TT + tBeg + 1) * 10 + o;
  float zc[8], zx[8];
#pragma unroll
  for (int j = 0; j < 8; ++j) { int ix = (j < nsteps) ? j : 0; zc[j] = zp[(size_t)ix * NC2]; }
  int NW = nsteps >> 3, tail = nsteps & 7;
  for (int i = 0; i < NW; ++i) {
    int nb0 = (i + 1) * 8;
#pragma unroll
    for (int j = 0; j < 8; ++j) { int ix = (nb0 + j < nsteps) ? (nb0 + j) : 0; zx[j] = zp[(size_t)ix * NC2]; }
#pragma unroll
    for (int j = 0; j < 8; ++j) { hh_step(V, m, n, h, y, zc[j]); *op = sigmoid3(V); op += 10; }
#pragma unroll
    for (int j = 0; j < 8; ++j) zc[j] = zx[j];
  }
  for (int j = 0; j < tail; ++j) { hh_step(V, m, n, h, y, zc[j]); *op = sigmoid3(V); op += 10; }
  SV[c2] = V; SM[c2] = m; SN[c2] = n; SH[c2] = h; SY[c2] = y;
}

// ---------- fused pipeline dispatch ----------
// Block order: [l1 | l2 | z2 | gemm] -- scans (critical path) get CUs first.
__global__ __launch_bounds__(256) void fused_pipe(
    const float* __restrict__ batch, const short* __restrict__ W1h,
    const short* __restrict__ W1l, const float* __restrict__ W2,
    float* __restrict__ z1s, float* __restrict__ T1s, float* __restrict__ z2s,
    float* __restrict__ out, float* __restrict__ stL1, float* __restrict__ stL2,
    int kG, int kL1, int kZ2, int kL2,
    int nL1, int nL2, int nZ2, int nG) {
  __shared__ __align__(16) char smem[30720];
  int bid = (int)blockIdx.x;
  if (bid < nL1) { l1_body(z1s, T1s, stL1, kL1, bid); return; }
  bid -= nL1;
  if (bid < nL2) { l2_body(z2s, out, stL2, kL2, bid); return; }
  bid -= nL2;
  if (bid < nZ2) { z2_body(T1s, W2, z2s, kZ2, bid, smem); return; }
  bid -= nZ2;
  if (bid < nG) { gemm_body(batch, W1h, W1l, z1s, kG, bid, smem); }
}

extern "C" void kernel_launch(void* const* d_in, const int* in_sizes, int n_in,
                              void* d_out, int out_size, void* d_ws, size_t ws_size,
                              hipStream_t stream) {
  (void)in_sizes; (void)n_in; (void)out_size; (void)ws_size;
  const float* batch = (const float*)d_in[0];
  const float* W1 = (const float*)d_in[1];
  const float* W2 = (const float*)d_in[2];
  float* out = (float*)d_out;

  // ws layout (~170 MB of ~2.45 GB): z1s | T1s | z2s | W1h | W1l | stL1 | stL2
  float* z1s = (float*)d_ws;                                  // (NB*CT1) x 100
  float* T1s = z1s + (size_t)NB * CT1 * 100;                  // CT2 x NC1
  float* z2s = T1s + (size_t)CT2 * NC1;                       // (CT2*NB) x 10
  short* W1h = (short*)(z2s + (size_t)CT2 * NC2);
  short* W1l = W1h + (size_t)NPAD * KPAD;
  float* stL1 = (float*)(W1l + (size_t)NPAD * KPAD);          // 5 x NC1
  float* stL2 = stL1 + 5 * NC1;                               // 5 x NC2

  prep_w1<<<dim3((NPAD * KPAD + 255) / 256), dim3(256), 0, stream>>>(W1, W1h, W1l);

  for (int d = 0; d <= NCHUNK + 2; ++d) {
    int kG = d, kL1 = d - 1, kZ2 = d - 2, kL2 = d - 3;
    int nG = (kG >= 0 && kG < NCHUNK) ? NB : 0;
    int nL1 = (kL1 >= 0 && kL1 < NCHUNK) ? (NC1 + 255) / 256 : 0;
    int nZ2 = 0;
    if (kZ2 >= 0 && kZ2 < NCHUNK) {
      int tBeg = kZ2 * S1;
      int tEnd = (tBeg + S1 < CT2) ? (tBeg + S1) : CT2;
      nZ2 = ((tEnd - tBeg) * NB + 255) / 256;
    }
    int nL2 = (kL2 >= 0 && kL2 < NCHUNK) ? (NC2 + 255) / 256 : 0;
    int grid = nL1 + nL2 + nZ2 + nG;
    if (grid == 0) continue;
    fused_pipe<<<dim3((unsigned)grid), dim3(256), 0, stream>>>(
        batch, W1h, W1l, W2, z1s, T1s, z2s, out, stL1, stL2,
        kG, kL1, kZ2, kL2, nL1, nL2, nZ2, nG);
  }
}